// Round 18
// baseline (220.408 us; speedup 1.0000x reference)
//
#include <hip/hip_runtime.h>
#include <math.h>

#define NN 4096
#define RB 128  // readout stage-1 blocks

typedef __attribute__((ext_vector_type(8))) short bf16x8;
typedef __attribute__((ext_vector_type(4))) float f32x4;

// ---------- helpers ----------
__device__ __forceinline__ unsigned encf(float f) {
  unsigned u = __float_as_uint(f);
  return (u & 0x80000000u) ? ~u : (u | 0x80000000u);
}
__device__ __forceinline__ float decf(unsigned u) {
  return __uint_as_float((u & 0x80000000u) ? (u ^ 0x80000000u) : ~u);
}
__device__ __forceinline__ unsigned short f2bf(float f) {
  unsigned u = __float_as_uint(f);
  return (unsigned short)((u + 0x7fffu + ((u >> 16) & 1u)) >> 16);
}

// ---------- pos = img @ Wp + bp  (+ init dmax in block 0) ----------
__global__ void k_pos(const float* img, const float* Wp, const float* bp, float* pos,
                      unsigned* dmax) {
  if (blockIdx.x == 0 && threadIdx.x == 0) *dmax = 0u;
  int t = blockIdx.x * 256 + threadIdx.x;
  if (t >= NN * 12) return;
  int i = t / 12, d = t % 12;
  float s = bp[d];
#pragma unroll
  for (int k = 0; k < 6; ++k) s += img[i * 6 + k] * Wp[k * 12 + d];
  pos[t] = s;
}

// ---------- attention, d=12, LDS-tiled keys, branch-free softmax ----------
__global__ __launch_bounds__(256) void k_attn3(const float* pos, float* out) {
  __shared__ float sp[12][256];
  int t = threadIdx.x, lane = t & 63, w = t >> 6;
  int ib = blockIdx.x * 8 + w * 2;  // 2 rows per wave, 8 per block
  float pi[2][12];
#pragma unroll
  for (int r = 0; r < 2; ++r)
#pragma unroll
    for (int d = 0; d < 12; ++d) pi[r][d] = pos[(ib + r) * 12 + d] * 0.28867513459481287f;
  float sl[2] = {0.f, 0.f};
  float acc[2][12] = {};
  const float4* p4 = (const float4*)pos;
  for (int kt = 0; kt < NN; kt += 256) {
    __syncthreads();  // previous tile fully consumed
    int j = kt + t;
    float4 a = p4[j * 3 + 0], b = p4[j * 3 + 1], c = p4[j * 3 + 2];
    sp[0][t] = a.x; sp[1][t] = a.y; sp[2][t] = a.z; sp[3][t] = a.w;
    sp[4][t] = b.x; sp[5][t] = b.y; sp[6][t] = b.z; sp[7][t] = b.w;
    sp[8][t] = c.x; sp[9][t] = c.y; sp[10][t] = c.z; sp[11][t] = c.w;
    __syncthreads();
#pragma unroll
    for (int q = 0; q < 4; ++q) {
      int jj = q * 64 + lane;
      float pj[12];
#pragma unroll
      for (int d = 0; d < 12; ++d) pj[d] = sp[d][jj];
#pragma unroll
      for (int r = 0; r < 2; ++r) {
        float s = 0.f;
#pragma unroll
        for (int d = 0; d < 12; ++d) s = fmaf(pi[r][d], pj[d], s);
        float e = __expf(s);
        sl[r] += e;
#pragma unroll
        for (int d = 0; d < 12; ++d) acc[r][d] = fmaf(e, pj[d], acc[r][d]);
      }
    }
  }
#pragma unroll
  for (int r = 0; r < 2; ++r) {
    float s = sl[r];
#pragma unroll
    for (int o = 32; o > 0; o >>= 1) s += __shfl_xor(s, o);
    float ad[12];
#pragma unroll
    for (int d = 0; d < 12; ++d) {
      ad[d] = acc[r][d];
#pragma unroll
      for (int o = 32; o > 0; o >>= 1) ad[d] += __shfl_xor(ad[d], o);
    }
    if (lane == 0) {
      float inv = 1.f / s;
#pragma unroll
      for (int d = 0; d < 12; ++d) out[(ib + r) * 12 + d] = ad[d] * inv;
    }
  }
}

// ---------- fused layernorms + sumsq + bf16 convert (shuffle reductions) ----------
__global__ __launch_bounds__(256) void k_lnx(const float* f, const float* g, const float* b,
                                             const float* p, const float* pg, const float* pb,
                                             float* x0, unsigned short* x0h, float* sqv,
                                             int* degA) {
  __shared__ float row[512];
  __shared__ float wrA[4], wrB[4], wrC[4];
  int i = blockIdx.x, t = threadIdx.x, lane = t & 63, w = t >> 6;
  if (t == 0) degA[i] = 0;
  float v1 = f[i * 500 + t];
  float v2 = (t < 244) ? f[i * 500 + 256 + t] : 0.f;
  float part = v1 + v2;
#pragma unroll
  for (int o = 32; o > 0; o >>= 1) part += __shfl_xor(part, o);
  if (lane == 0) wrA[w] = part;
  __syncthreads();
  float m = (wrA[0] + wrA[1] + wrA[2] + wrA[3]) * (1.f / 500.f);
  float d1 = v1 - m, d2 = v2 - m;
  float pvv = d1 * d1 + ((t < 244) ? d2 * d2 : 0.f);
#pragma unroll
  for (int o = 32; o > 0; o >>= 1) pvv += __shfl_xor(pvv, o);
  if (lane == 0) wrB[w] = pvv;
  __syncthreads();
  float scale = 1.f / sqrtf((wrB[0] + wrB[1] + wrB[2] + wrB[3]) * (1.f / 500.f) + 1e-5f);
  row[t] = d1 * scale * g[t] + b[t];
  if (t < 244) row[256 + t] = d2 * scale * g[256 + t] + b[256 + t];
  if (t >= 244) {  // threads 244..255 handle the 12-wide pos layernorm
    int tt = t - 244;
    float pv[12], pm = 0.f;
#pragma unroll
    for (int d = 0; d < 12; ++d) { pv[d] = p[i * 12 + d]; pm += pv[d]; }
    pm *= (1.f / 12.f);
    float pvar = 0.f;
#pragma unroll
    for (int d = 0; d < 12; ++d) { float dd = pv[d] - pm; pvar += dd * dd; }
    pvar *= (1.f / 12.f);
    float ps = 1.f / sqrtf(pvar + 1e-5f);
    row[500 + tt] = (pv[tt] - pm) * ps * pg[tt] + pb[tt];
  }
  __syncthreads();
  float a = row[t], c = row[256 + t];
  float sq = a * a + c * c;
#pragma unroll
  for (int o = 32; o > 0; o >>= 1) sq += __shfl_xor(sq, o);
  if (lane == 0) wrC[w] = sq;
  __syncthreads();
  if (t == 0) sqv[i] = wrC[0] + wrC[1] + wrC[2] + wrC[3];
  x0[(size_t)i * 512 + t] = a;
  x0[(size_t)i * 512 + 256 + t] = c;
  x0h[(size_t)i * 512 + t] = f2bf(a);
  x0h[(size_t)i * 512 + 256 + t] = f2bf(c);
}

// ---------- MFMA d2 tiles (128x128, upper tile pairs): max / mask pass ----------
// T4 pipeline: double-buffered LDS; issue next panel's 8 DMAs, COUNTED vmcnt(8),
// sched_barrier(0), raw s_barrier; T5 setprio(1) around the MFMA cluster.
// Source pre-swizzled (chunk = (lane&7)^(row&7)); reads apply the same XOR.
// Pass A records per-tile min over gi<gj; pass B skips GEMM when tileMin >= thr,
// zeroes mirror tiles, and atomically accumulates integer deg[j].
#define BK 64
template <bool MASK>
__global__ __launch_bounds__(256) void k_d2m(const unsigned short* X, const float* sqv,
                                             unsigned* dmax, float* tileMin,
                                             unsigned char* ATm, int* deg) {
  __shared__ unsigned short As[2][128 * BK];
  __shared__ unsigned short Bs[2][128 * BK];
  __shared__ float wmax[4], wmin[4];
  const int NT = NN / 128;
  int bid0 = blockIdx.x;
  int bid = (bid0 & 7) * 66 + (bid0 >> 3);  // 528 total, bijective
  int ti = 0, rem = bid;
  while (rem >= NT - ti) { rem -= NT - ti; ++ti; }
  int tj = ti + rem;
  int t = threadIdx.x, lane = t & 63, w = t >> 6;
  int wr = w >> 1, wc = w & 1;  // wave's 64x64 sub-tile
  const unsigned short* Abase = X + (size_t)ti * 128 * 512;
  const unsigned short* Bbase = X + (size_t)tj * 128 * 512;
  int lr = lane >> 3, lc = lane & 7;

  float thr = 0.f;
  if (MASK) {
    thr = 0.5f * decf(*dmax);
    uint4 z = make_uint4(0u, 0u, 0u, 0u);
    if (ti != tj) {  // mirror tile (rows ti, cols tj) never receives mask writes
#pragma unroll
      for (int q0 = 0; q0 < 4; ++q0) {
        int q = t + q0 * 256; int r = q >> 3, c4 = q & 7;
        *(uint4*)(ATm + (size_t)(ti * 128 + r) * NN + tj * 128 + c4 * 16) = z;
      }
    }
    if (tileMin[blockIdx.x] >= thr) {  // no element can pass -> zero tile, skip GEMM
#pragma unroll
      for (int q0 = 0; q0 < 4; ++q0) {
        int q = t + q0 * 256; int r = q >> 3, c4 = q & 7;
        *(uint4*)(ATm + (size_t)(tj * 128 + r) * NN + ti * 128 + c4 * 16) = z;
      }
      return;
    }
  }

  auto stage = [&](int buf, int k0) {  // 8 DMAs per wave (4x A + 4x B)
#pragma unroll
    for (int i = 0; i < 4; ++i) {
      int q = w * 4 + i;
      int r = q * 8 + lr;
      int cs = lc ^ (r & 7);  // pre-swizzled source chunk
      __builtin_amdgcn_global_load_lds(
          (const __attribute__((address_space(1))) unsigned int*)(Abase + (size_t)r * 512 + k0 + cs * 8),
          (__attribute__((address_space(3))) unsigned int*)(&As[buf][q * 512]), 16, 0, 0);
      __builtin_amdgcn_global_load_lds(
          (const __attribute__((address_space(1))) unsigned int*)(Bbase + (size_t)r * 512 + k0 + cs * 8),
          (__attribute__((address_space(3))) unsigned int*)(&Bs[buf][q * 512]), 16, 0, 0);
    }
  };

  stage(0, 0);  // 8 outstanding

  f32x4 acc[4][4] = {};
  int rl = lane & 15, kg = lane >> 4;
  for (int step = 0; step < 8; ++step) {
    int cur = step & 1;
    if (step < 7) {
      stage(cur ^ 1, (step + 1) * BK);  // +8 in flight (16 total)
      asm volatile("s_waitcnt vmcnt(8)" ::: "memory");  // cur's 8 retired (in-order)
    } else {
      asm volatile("s_waitcnt vmcnt(0)" ::: "memory");
    }
    __builtin_amdgcn_sched_barrier(0);
    __builtin_amdgcn_s_barrier();  // all waves' cur panel visible
    __builtin_amdgcn_s_setprio(1);
#pragma unroll
    for (int ks = 0; ks < 2; ++ks) {
      bf16x8 af[4], bq[4];
#pragma unroll
      for (int f = 0; f < 4; ++f) {
        int rA = wr * 64 + f * 16 + rl;
        af[f] = *(const bf16x8*)(&As[cur][rA * BK + (((ks * 4 + kg) ^ (rA & 7)) << 3)]);
        int rB = wc * 64 + f * 16 + rl;
        bq[f] = *(const bf16x8*)(&Bs[cur][rB * BK + (((ks * 4 + kg) ^ (rB & 7)) << 3)]);
      }
#pragma unroll
      for (int a = 0; a < 4; ++a)
#pragma unroll
        for (int b = 0; b < 4; ++b)
          acc[a][b] = __builtin_amdgcn_mfma_f32_16x16x32_bf16(af[a], bq[b], acc[a][b], 0, 0, 0);
    }
    __builtin_amdgcn_s_setprio(0);
    __builtin_amdgcn_sched_barrier(0);  // pin ds_reads before the reuse barrier
    __builtin_amdgcn_s_barrier();       // all reads of cur done before its overwrite
  }
  // C/D layout: col = lane&15, row = (lane>>4)*4 + reg   [m89/m91 verified]
  int rbase = ti * 128 + wr * 64 + ((lane >> 4) << 2);
  int cbase = tj * 128 + wc * 64 + (lane & 15);
  if (!MASK) {
    float lm = -1e30f, lmin = 1e30f;
#pragma unroll
    for (int a = 0; a < 4; ++a) {
      float si[4];
#pragma unroll
      for (int r = 0; r < 4; ++r) si[r] = sqv[rbase + a * 16 + r];
#pragma unroll
      for (int b = 0; b < 4; ++b) {
        int gj = cbase + b * 16;
        float sj = sqv[gj];
#pragma unroll
        for (int r = 0; r < 4; ++r) {
          float d2v = si[r] - 2.f * acc[a][b][r] + sj;
          lm = fmaxf(lm, d2v);
          if (rbase + a * 16 + r < gj) lmin = fminf(lmin, d2v);
        }
      }
    }
#pragma unroll
    for (int o = 32; o > 0; o >>= 1) {
      lm = fmaxf(lm, __shfl_xor(lm, o));
      lmin = fminf(lmin, __shfl_xor(lmin, o));
    }
    if (lane == 0) { wmax[w] = lm; wmin[w] = lmin; }
    __syncthreads();
    if (t == 0) {
      atomicMax(dmax, encf(fmaxf(fmaxf(wmax[0], wmax[1]), fmaxf(wmax[2], wmax[3]))));
      tileMin[blockIdx.x] = fminf(fminf(wmin[0], wmin[1]), fminf(wmin[2], wmin[3]));
    }
  } else {
#pragma unroll
    for (int b = 0; b < 4; ++b) {
      int gj = cbase + b * 16;
      float sj = sqv[gj];
      int rowcnt = 0;
#pragma unroll
      for (int a = 0; a < 4; ++a) {
        int gi0 = rbase + a * 16;
        union { unsigned char c[4]; unsigned u; } m4;
#pragma unroll
        for (int r = 0; r < 4; ++r) {
          float d2v = sqv[gi0 + r] - 2.f * acc[a][b][r] + sj;
          unsigned char mv = (d2v < thr && (gi0 + r) < gj) ? 1 : 0;
          m4.c[r] = mv; rowcnt += mv;
        }
        *(unsigned*)(ATm + (size_t)gj * NN + gi0) = m4.u;  // AT[j][i..i+3]
      }
      if (rowcnt) atomicAdd(&deg[gj], rowcnt);
    }
  }
}

// ---------- fp32 GEMM + row scale: C[i][c] = (A@B)[i][c] / sqrt(1+deg[i]) ----------
// 16x64 tile (grid x2 vs 32x64 -> 4 blocks/CU). A scalar broadcast read (same addr
// within 16-lane group = LDS broadcast), B float4. Same kk order -> bit-identical C.
__global__ __launch_bounds__(256) void k_gemm(const float* A, const float* B, const int* deg,
                                              float* C, int M, int N, int K) {
  __shared__ float Ast[16][17];
  __shared__ float Bs[16][64];
  int t = threadIdx.x, tx = t & 15, ty = t >> 4;
  int nbx = N >> 6;
  int total = gridDim.x;
  int bid0 = blockIdx.x;
  int bid = (bid0 & 7) * (total >> 3) + (bid0 >> 3);  // bijective: total%8==0
  int m0 = (bid / nbx) * 16, n0 = (bid % nbx) * 64;
  int ar = t >> 4, ac = t & 15;       // A stage: 1 float/thread (transposed write)
  int br = t >> 4, bc = (t & 15) * 4; // B stage: 4 floats/thread
  float ra = A[(size_t)(m0 + ar) * K + ac];
  float4 rb = *(const float4*)(B + (size_t)br * N + n0 + bc);
  float acc[4] = {};
  for (int k0 = 0; k0 < K; k0 += 16) {
    Ast[ac][ar] = ra;
    *(float4*)(&Bs[br][bc]) = rb;
    __syncthreads();
    if (k0 + 16 < K) {  // prefetch next panel (overlaps compute)
      ra = A[(size_t)(m0 + ar) * K + k0 + 16 + ac];
      rb = *(const float4*)(B + (size_t)(k0 + 16 + br) * N + n0 + bc);
    }
#pragma unroll
    for (int kk = 0; kk < 16; ++kk) {
      float av = Ast[kk][ty];
      float4 bv = *(const float4*)(&Bs[kk][tx * 4]);
      acc[0] = fmaf(av, bv.x, acc[0]);
      acc[1] = fmaf(av, bv.y, acc[1]);
      acc[2] = fmaf(av, bv.z, acc[2]);
      acc[3] = fmaf(av, bv.w, acc[3]);
    }
    __syncthreads();
  }
  float dv = 1.f / sqrtf((float)(1 + deg[m0 + ty]));
#pragma unroll
  for (int b2 = 0; b2 < 4; ++b2)
    C[(size_t)(m0 + ty) * N + n0 + tx * 4 + b2] = acc[b2] * dv;
}

// ---------- fused: xg row + relu + y2 + (deg==0) score ----------
// Fast path: deg[j]==0 -> no neighbors, skip the mask scan; also writes score[j]
// (s=0 -> formula identical to k_scorek's). k_scorek handles only deg>0 rows.
__global__ __launch_bounds__(256) void k_agg(const float* y, const unsigned char* ATm,
                                             const int* deg, const float* bias,
                                             const float* Wpool, const float* bp,
                                             float* out, float* y2, float* score, int n) {
  __shared__ unsigned char mrow[256];
  __shared__ int s_any;
  __shared__ float wred[4];
  int j = blockIdx.x, t = threadIdx.x, lane = t & 63, w = t >> 6;
  int dg = deg[j];
  float dj = 1.f / sqrtf((float)(1 + dg));
  float acc = y[(size_t)j * 256 + t];
  if (dg != 0) {
    for (int i0 = 0; i0 < n; i0 += 256) {
      if (t == 0) s_any = 0;
      __syncthreads();
      unsigned char m = ATm[(size_t)j * n + i0 + t];
      mrow[t] = m;
      if (m) s_any = 1;
      __syncthreads();
      if (s_any) {
        for (int u = 0; u < 256; ++u)
          if (mrow[u]) acc += y[(size_t)(i0 + u) * 256 + t];
      }
      __syncthreads();
    }
  }
  float o = fmaxf(dj * acc + bias[t], 0.f);
  out[(size_t)j * 256 + t] = o;
  float rv = o * Wpool[t];
#pragma unroll
  for (int os = 32; os > 0; os >>= 1) rv += __shfl_xor(rv, os);
  if (lane == 0) wred[w] = rv;
  __syncthreads();
  if (t == 0) {
    float yy = dj * (wred[0] + wred[1] + wred[2] + wred[3]);
    y2[j] = yy;
    if (dg == 0) score[j] = tanhf(dj * yy + bp[0]);  // s=0: identical to scorek
  }
}

// ---------- score[j] for deg>0 rows only (deg==0 written by k_agg) ----------
__global__ __launch_bounds__(256) void k_scorek(const float* y2, const unsigned char* ATm,
                                                const int* deg, const float* bp,
                                                float* score, int n) {
  int w = threadIdx.x >> 6, lane = threadIdx.x & 63;
  int j = blockIdx.x * 4 + w;
  if (j >= n) return;
  int dg = deg[j];
  if (dg == 0) return;  // agg already wrote score[j]
  float dj = 1.f / sqrtf((float)(1 + dg));
  float s = 0.f;
  const uint4* row = (const uint4*)(ATm + (size_t)j * n);
  for (int p = lane; p < n / 16; p += 64) {
    uint4 v = row[p];
    if (v.x | v.y | v.z | v.w) {
      int base = p * 16;
#pragma unroll
      for (int q = 0; q < 4; ++q) {
        unsigned u = (&v.x)[q];
#pragma unroll
        for (int b2 = 0; b2 < 4; ++b2)
          if ((u >> (8 * b2)) & 0xffu) s += y2[base + q * 4 + b2];
      }
    }
  }
  for (int sh = 32; sh > 0; sh >>= 1) s += __shfl_down(s, sh);
  if (lane == 0) score[j] = tanhf(dj * (y2[j] + s) + bp[0]);
}

// ---------- radix-select top-k (exact PyG set semantics; output in index order) ----------
__global__ __launch_bounds__(1024) void k_topsel(const float* score, int n, int k,
                                                 int* perm, float* vals) {
  __shared__ unsigned keys[4096];
  __shared__ unsigned hist[256];
  __shared__ unsigned s_state[2];  // [0]=prefix(cutoff), [1]=need(ties to take)
  __shared__ unsigned woff[16];
  int t = threadIdx.x, lane = t & 63, w = t >> 6;
  for (int i = t; i < 4096; i += 1024) keys[i] = (i < n) ? encf(score[i]) : 0u;
  if (t == 0) { s_state[0] = 0u; s_state[1] = (unsigned)k; }
  __syncthreads();

  for (int pass = 0; pass < 4; ++pass) {
    int shift = 24 - pass * 8;
    if (t < 256) hist[t] = 0u;
    __syncthreads();
    unsigned prefix = s_state[0];
    unsigned need = s_state[1];
    unsigned pmask = pass ? (0xFFFFFFFFu << (shift + 8)) : 0u;
    for (int i = t; i < n; i += 1024) {
      unsigned kk = keys[i];
      if ((kk & pmask) == prefix) atomicAdd(&hist[(kk >> shift) & 255u], 1u);
    }
    __syncthreads();
    if (w == 0) {
      unsigned h[4], suf[4];
#pragma unroll
      for (int r = 0; r < 4; ++r) h[r] = hist[lane * 4 + r];
      suf[3] = h[3]; suf[2] = h[2] + suf[3]; suf[1] = h[1] + suf[2]; suf[0] = h[0] + suf[1];
      unsigned lsum = suf[0];
      unsigned s = lsum;
#pragma unroll
      for (int off = 1; off < 64; off <<= 1) {
        unsigned o = __shfl_down(s, off);
        if (lane + off < 64) s += o;
      }
      unsigned Hl = s - lsum;
      int cand = -1; unsigned cumAt = 0, histAt = 0;
#pragma unroll
      for (int r = 0; r < 4; ++r) {
        unsigned c = Hl + suf[r];
        if (c >= need) { cand = lane * 4 + r; cumAt = c; histAt = h[r]; }
      }
      int gmax = cand;
#pragma unroll
      for (int off = 32; off > 0; off >>= 1) {
        int o = __shfl_xor(gmax, off);
        gmax = o > gmax ? o : gmax;
      }
      if (cand == gmax && cand >= 0) {
        s_state[0] = prefix | ((unsigned)cand << shift);
        s_state[1] = need - (cumAt - histAt);
      }
    }
    __syncthreads();
  }
  unsigned cutoff = s_state[0];
  unsigned tcount = s_state[1];
  unsigned G = (unsigned)k - tcount;

  int i0 = t * 4;
  unsigned loc[4], cnt = 0;
#pragma unroll
  for (int r = 0; r < 4; ++r) {
    unsigned kk = keys[i0 + r];
    unsigned g = (kk > cutoff) ? 1u : 0u;
    unsigned e = (kk == cutoff) ? 1u : 0u;
    loc[r] = cnt;
    cnt += (g << 16) | e;
  }
  unsigned inc = cnt;
#pragma unroll
  for (int off = 1; off < 64; off <<= 1) {
    unsigned o = __shfl_up(inc, off);
    if (lane >= off) inc += o;
  }
  if (lane == 63) woff[w] = inc;
  __syncthreads();
  if (t == 0) {
    unsigned run = 0;
    for (int q = 0; q < 16; ++q) { unsigned v = woff[q]; woff[q] = run; run += v; }
  }
  __syncthreads();
  unsigned base = woff[w] + (inc - cnt);
#pragma unroll
  for (int r = 0; r < 4; ++r) {
    unsigned kk = keys[i0 + r];
    unsigned p = base + loc[r];
    if (kk > cutoff) {
      unsigned pos = p >> 16;
      perm[pos] = i0 + r; vals[pos] = decf(kk);
    } else if (kk == cutoff) {
      unsigned pe = p & 0xffffu;
      if (pe < tcount) { perm[G + pe] = i0 + r; vals[G + pe] = decf(kk); }
    }
  }
}

// ---------- merged pool: blocks [0,RB) gather+readout partials; [RB,RB+kn) gatherA ----------
// xp==nullptr (last layer): skip xp stores (only partials consumed).
// gatherA fast path: degCur[src]==0 -> row NEVER read downstream (all consumers gated
// by degNext[c]==0), so skip even the zero writes.
__global__ __launch_bounds__(256) void k_pool(const float* xg, const int* perm, const float* vals,
                                              float* xp, float* pmax, float* psum, int k,
                                              const unsigned char* ATold, const int* degCur,
                                              unsigned char* ATnew, int* degNext, int nold) {
  __shared__ int sperm[4096];
  __shared__ int redi[256];
  int b = blockIdx.x, t = threadIdx.x;
  if (b < RB) {  // gather xp rows + per-block max/sum partials
    float m = -1e30f, s = 0.f;
    for (int r = b; r < k; r += RB) {
      float v = xg[(size_t)perm[r] * 256 + t] * vals[r];
      if (xp) xp[(size_t)r * 256 + t] = v;
      m = fmaxf(m, v); s += v;
    }
    pmax[b * 256 + t] = m; psum[b * 256 + t] = s;
    return;
  }
  // gatherA: ATnew[c][r] = ATold[perm[c]][perm[r]], degNext[c] = row count
  int c = b - RB;
  int src = perm[c];
  if (degCur[src] == 0) {  // empty source row: never read (deg gating) -> no writes
    if (t == 0) degNext[c] = 0;
    return;
  }
  for (int r = t; r < k; r += 256) sperm[r] = perm[r];
  __syncthreads();
  unsigned char* orow = ATnew + (size_t)c * k;
  const unsigned char* row = ATold + (size_t)src * nold;
  int cnt = 0;
  for (int r = t; r < k; r += 256) { unsigned char v = row[sperm[r]]; orow[r] = v; cnt += v; }
  redi[t] = cnt; __syncthreads();
  for (int s = 128; s > 0; s >>= 1) { if (t < s) redi[t] += redi[t + s]; __syncthreads(); }
  if (t == 0) degNext[c] = redi[0];
}

// ---------- single deferred readout finalize for all 3 layers ----------
__global__ void k_rfin3(const float* pm0, const float* ps0, int k0,
                        const float* pm1, const float* ps1, int k1,
                        const float* pm2, const float* ps2, int k2, float* out) {
  int t = threadIdx.x;
  float m0 = -1e30f, s0 = 0.f, m1 = -1e30f, s1 = 0.f, m2 = -1e30f, s2 = 0.f;
  for (int q = 0; q < RB; ++q) {
    m0 = fmaxf(m0, pm0[q * 256 + t]); s0 += ps0[q * 256 + t];
    m1 = fmaxf(m1, pm1[q * 256 + t]); s1 += ps1[q * 256 + t];
    m2 = fmaxf(m2, pm2[q * 256 + t]); s2 += ps2[q * 256 + t];
  }
  out[t] = m0 + m1 + m2;  // same left-assoc order as per-layer +=
  out[256 + t] = s0 / (float)k0 + s1 / (float)k1 + s2 / (float)k2;
}

// ---------- host-side layer driver ----------
static void run_layer(hipStream_t stream, const float* x_in, int n, int inC,
                      const float* W, const float* b, const float* Wpool, const float* bpool,
                      int k, const unsigned char* ATcur, unsigned char* ATnext,
                      const int* degCur, int* degNext,
                      float* ybuf, float* xg, float* xp, float* y2,
                      float* score, int* perm, float* vals, float* pmax, float* psum) {
  k_gemm<<<(n / 16) * 4, 256, 0, stream>>>(x_in, W, degCur, ybuf, n, 256, inC);
  k_agg<<<n, 256, 0, stream>>>(ybuf, ATcur, degCur, b, Wpool, bpool, xg, y2, score, n);
  k_scorek<<<n / 4, 256, 0, stream>>>(y2, ATcur, degCur, bpool, score, n);
  k_topsel<<<1, 1024, 0, stream>>>(score, n, k, perm, vals);
  int grid = RB + (ATnext ? k : 0);
  k_pool<<<grid, 256, 0, stream>>>(xg, perm, vals, ATnext ? xp : nullptr, pmax, psum, k,
                                   ATcur, degCur, ATnext, degNext, n);
}

extern "C" void kernel_launch(void* const* d_in, const int* in_sizes, int n_in,
                              void* d_out, int out_size, void* d_ws, size_t ws_size,
                              hipStream_t stream) {
  const float* feature = (const float*)d_in[0];
  const float* img     = (const float*)d_in[1];
  const float* Wp      = (const float*)d_in[2];
  const float* bp      = (const float*)d_in[3];
  const float* ln_f_g  = (const float*)d_in[4];
  const float* ln_f_b  = (const float*)d_in[5];
  const float* ln_p_g  = (const float*)d_in[6];
  const float* ln_p_b  = (const float*)d_in[7];
  const float* W1 = (const float*)d_in[8];   const float* b1 = (const float*)d_in[9];
  const float* Wpool1 = (const float*)d_in[10]; const float* bpool1 = (const float*)d_in[11];
  const float* W2 = (const float*)d_in[12];  const float* b2 = (const float*)d_in[13];
  const float* Wpool2 = (const float*)d_in[14]; const float* bpool2 = (const float*)d_in[15];
  const float* W3 = (const float*)d_in[16];  const float* b3 = (const float*)d_in[17];
  const float* Wpool3 = (const float*)d_in[18]; const float* bpool3 = (const float*)d_in[19];
  float* out = (float*)d_out;
  (void)in_sizes; (void)n_in; (void)out_size; (void)ws_size;

  char* w = (char*)d_ws;
  size_t off = 0;
  auto alloc = [&](size_t bytes) -> char* {
    off = (off + 255) & ~(size_t)255;
    char* p = w + off;
    off += bytes;
    return p;
  };
  float* pos0 = (float*)alloc((size_t)NN * 12 * 4);
  float* pos1 = (float*)alloc((size_t)NN * 12 * 4);
  float* x0   = (float*)alloc((size_t)NN * 512 * 4);
  unsigned short* x0h = (unsigned short*)alloc((size_t)NN * 512 * 2);
  float* sqv  = (float*)alloc((size_t)NN * 4);
  unsigned* dmax = (unsigned*)alloc(4);
  float* tileMin = (float*)alloc(528 * 4);
  int* degA = (int*)alloc((size_t)NN * 4);
  int* degB = (int*)alloc((size_t)NN * 4);
  float* ybuf = (float*)alloc((size_t)NN * 256 * 4);
  float* xg   = (float*)alloc((size_t)NN * 256 * 4);
  float* xp   = (float*)alloc((size_t)NN * 256 * 4);
  float* y2   = (float*)alloc((size_t)NN * 4);
  float* score= (float*)alloc((size_t)NN * 4);
  int*   perm = (int*)alloc((size_t)NN * 4);
  float* vals = (float*)alloc((size_t)NN * 4);
  float* pmax0 = (float*)alloc(RB * 256 * 4);
  float* psum0 = (float*)alloc(RB * 256 * 4);
  float* pmax1 = (float*)alloc(RB * 256 * 4);
  float* psum1 = (float*)alloc(RB * 256 * 4);
  float* pmax2 = (float*)alloc(RB * 256 * 4);
  float* psum2 = (float*)alloc(RB * 256 * 4);
  unsigned char* ATa = (unsigned char*)alloc((size_t)NN * NN);
  unsigned char* ATb = (unsigned char*)alloc((size_t)3072 * 3072);

  // preamble (init fused into k_pos; lnx zeroes degA)
  k_pos<<<(NN * 12 + 255) / 256, 256, 0, stream>>>(img, Wp, bp, pos0, dmax);
  k_attn3<<<NN / 8, 256, 0, stream>>>(pos0, pos1);
  k_lnx<<<NN, 256, 0, stream>>>(feature, ln_f_g, ln_f_b, pos1, ln_p_g, ln_p_b,
                                x0, x0h, sqv, degA);

  // edge construction via MFMA: max+tileMin pass, then pruned mask pass (+deg atomics)
  const int NT = NN / 128, TT = NT * (NT + 1) / 2;  // 32, 528
  k_d2m<false><<<TT, 256, 0, stream>>>(x0h, sqv, dmax, tileMin, nullptr, nullptr);
  k_d2m<true><<<TT, 256, 0, stream>>>(x0h, sqv, dmax, tileMin, ATa, degA);

  // three GCN + SAGPool + readout layers (readout finalize deferred to k_rfin3)
  run_layer(stream, x0, 4096, 512, W1, b1, Wpool1, bpool1, 3072, ATa, ATb, degA, degB,
            ybuf, xg, xp, y2, score, perm, vals, pmax0, psum0);
  run_layer(stream, xp, 3072, 256, W2, b2, Wpool2, bpool2, 2304, ATb, ATa, degB, degA,
            ybuf, xg, xp, y2, score, perm, vals, pmax1, psum1);
  run_layer(stream, xp, 2304, 256, W3, b3, Wpool3, bpool3, 1728, ATa, nullptr, degA, nullptr,
            ybuf, xg, xp, y2, score, perm, vals, pmax2, psum2);
  k_rfin3<<<1, 256, 0, stream>>>(pmax0, psum0, 3072, pmax1, psum1, 2304,
                                 pmax2, psum2, 1728, out);
}

// Round 19
// 215.286 us; speedup vs baseline: 1.0238x; 1.0238x over previous
//
#include <hip/hip_runtime.h>
#include <math.h>

#define NN 4096
#define RB 128  // readout stage-1 blocks

typedef __attribute__((ext_vector_type(8))) short bf16x8;
typedef __attribute__((ext_vector_type(4))) float f32x4;

// ---------- helpers ----------
__device__ __forceinline__ unsigned encf(float f) {
  unsigned u = __float_as_uint(f);
  return (u & 0x80000000u) ? ~u : (u | 0x80000000u);
}
__device__ __forceinline__ float decf(unsigned u) {
  return __uint_as_float((u & 0x80000000u) ? (u ^ 0x80000000u) : ~u);
}
__device__ __forceinline__ unsigned short f2bf(float f) {
  unsigned u = __float_as_uint(f);
  return (unsigned short)((u + 0x7fffu + ((u >> 16) & 1u)) >> 16);
}

// ---------- pos = img @ Wp + bp  (+ init dmax in block 0) ----------
__global__ void k_pos(const float* img, const float* Wp, const float* bp, float* pos,
                      unsigned* dmax) {
  if (blockIdx.x == 0 && threadIdx.x == 0) *dmax = 0u;
  int t = blockIdx.x * 256 + threadIdx.x;
  if (t >= NN * 12) return;
  int i = t / 12, d = t % 12;
  float s = bp[d];
#pragma unroll
  for (int k = 0; k < 6; ++k) s += img[i * 6 + k] * Wp[k * 12 + d];
  pos[t] = s;
}

// ---------- attention, d=12, LDS-tiled keys, branch-free softmax ----------
__global__ __launch_bounds__(256) void k_attn3(const float* pos, float* out) {
  __shared__ float sp[12][256];
  int t = threadIdx.x, lane = t & 63, w = t >> 6;
  int ib = blockIdx.x * 8 + w * 2;  // 2 rows per wave, 8 per block
  float pi[2][12];
#pragma unroll
  for (int r = 0; r < 2; ++r)
#pragma unroll
    for (int d = 0; d < 12; ++d) pi[r][d] = pos[(ib + r) * 12 + d] * 0.28867513459481287f;
  float sl[2] = {0.f, 0.f};
  float acc[2][12] = {};
  const float4* p4 = (const float4*)pos;
  for (int kt = 0; kt < NN; kt += 256) {
    __syncthreads();  // previous tile fully consumed
    int j = kt + t;
    float4 a = p4[j * 3 + 0], b = p4[j * 3 + 1], c = p4[j * 3 + 2];
    sp[0][t] = a.x; sp[1][t] = a.y; sp[2][t] = a.z; sp[3][t] = a.w;
    sp[4][t] = b.x; sp[5][t] = b.y; sp[6][t] = b.z; sp[7][t] = b.w;
    sp[8][t] = c.x; sp[9][t] = c.y; sp[10][t] = c.z; sp[11][t] = c.w;
    __syncthreads();
#pragma unroll
    for (int q = 0; q < 4; ++q) {
      int jj = q * 64 + lane;
      float pj[12];
#pragma unroll
      for (int d = 0; d < 12; ++d) pj[d] = sp[d][jj];
#pragma unroll
      for (int r = 0; r < 2; ++r) {
        float s = 0.f;
#pragma unroll
        for (int d = 0; d < 12; ++d) s = fmaf(pi[r][d], pj[d], s);
        float e = __expf(s);
        sl[r] += e;
#pragma unroll
        for (int d = 0; d < 12; ++d) acc[r][d] = fmaf(e, pj[d], acc[r][d]);
      }
    }
  }
#pragma unroll
  for (int r = 0; r < 2; ++r) {
    float s = sl[r];
#pragma unroll
    for (int o = 32; o > 0; o >>= 1) s += __shfl_xor(s, o);
    float ad[12];
#pragma unroll
    for (int d = 0; d < 12; ++d) {
      ad[d] = acc[r][d];
#pragma unroll
      for (int o = 32; o > 0; o >>= 1) ad[d] += __shfl_xor(ad[d], o);
    }
    if (lane == 0) {
      float inv = 1.f / s;
#pragma unroll
      for (int d = 0; d < 12; ++d) out[(ib + r) * 12 + d] = ad[d] * inv;
    }
  }
}

// ---------- fused layernorms + sumsq + bf16 convert (shuffle reductions) ----------
__global__ __launch_bounds__(256) void k_lnx(const float* f, const float* g, const float* b,
                                             const float* p, const float* pg, const float* pb,
                                             float* x0, unsigned short* x0h, float* sqv,
                                             int* degA) {
  __shared__ float row[512];
  __shared__ float wrA[4], wrB[4], wrC[4];
  int i = blockIdx.x, t = threadIdx.x, lane = t & 63, w = t >> 6;
  if (t == 0) degA[i] = 0;
  float v1 = f[i * 500 + t];
  float v2 = (t < 244) ? f[i * 500 + 256 + t] : 0.f;
  float part = v1 + v2;
#pragma unroll
  for (int o = 32; o > 0; o >>= 1) part += __shfl_xor(part, o);
  if (lane == 0) wrA[w] = part;
  __syncthreads();
  float m = (wrA[0] + wrA[1] + wrA[2] + wrA[3]) * (1.f / 500.f);
  float d1 = v1 - m, d2 = v2 - m;
  float pvv = d1 * d1 + ((t < 244) ? d2 * d2 : 0.f);
#pragma unroll
  for (int o = 32; o > 0; o >>= 1) pvv += __shfl_xor(pvv, o);
  if (lane == 0) wrB[w] = pvv;
  __syncthreads();
  float scale = 1.f / sqrtf((wrB[0] + wrB[1] + wrB[2] + wrB[3]) * (1.f / 500.f) + 1e-5f);
  row[t] = d1 * scale * g[t] + b[t];
  if (t < 244) row[256 + t] = d2 * scale * g[256 + t] + b[256 + t];
  if (t >= 244) {  // threads 244..255 handle the 12-wide pos layernorm
    int tt = t - 244;
    float pv[12], pm = 0.f;
#pragma unroll
    for (int d = 0; d < 12; ++d) { pv[d] = p[i * 12 + d]; pm += pv[d]; }
    pm *= (1.f / 12.f);
    float pvar = 0.f;
#pragma unroll
    for (int d = 0; d < 12; ++d) { float dd = pv[d] - pm; pvar += dd * dd; }
    pvar *= (1.f / 12.f);
    float ps = 1.f / sqrtf(pvar + 1e-5f);
    row[500 + tt] = (pv[tt] - pm) * ps * pg[tt] + pb[tt];
  }
  __syncthreads();
  float a = row[t], c = row[256 + t];
  float sq = a * a + c * c;
#pragma unroll
  for (int o = 32; o > 0; o >>= 1) sq += __shfl_xor(sq, o);
  if (lane == 0) wrC[w] = sq;
  __syncthreads();
  if (t == 0) sqv[i] = wrC[0] + wrC[1] + wrC[2] + wrC[3];
  x0[(size_t)i * 512 + t] = a;
  x0[(size_t)i * 512 + 256 + t] = c;
  x0h[(size_t)i * 512 + t] = f2bf(a);
  x0h[(size_t)i * 512 + 256 + t] = f2bf(c);
}

// ---------- MFMA d2 tiles (128x128, upper tile pairs): max / mask pass ----------
// T4 pipeline: double-buffered LDS; issue next panel's 8 DMAs, COUNTED vmcnt(8),
// sched_barrier(0), raw s_barrier; T5 setprio(1) around the MFMA cluster.
// Source pre-swizzled (chunk = (lane&7)^(row&7)); reads apply the same XOR.
// Pass A records per-tile min over gi<gj; pass B skips GEMM when tileMin >= thr,
// zeroes mirror tiles, and atomically accumulates integer deg[j].
#define BK 64
template <bool MASK>
__global__ __launch_bounds__(256) void k_d2m(const unsigned short* X, const float* sqv,
                                             unsigned* dmax, float* tileMin,
                                             unsigned char* ATm, int* deg) {
  __shared__ unsigned short As[2][128 * BK];
  __shared__ unsigned short Bs[2][128 * BK];
  __shared__ float wmax[4], wmin[4];
  const int NT = NN / 128;
  int bid0 = blockIdx.x;
  int bid = (bid0 & 7) * 66 + (bid0 >> 3);  // 528 total, bijective
  int ti = 0, rem = bid;
  while (rem >= NT - ti) { rem -= NT - ti; ++ti; }
  int tj = ti + rem;
  int t = threadIdx.x, lane = t & 63, w = t >> 6;
  int wr = w >> 1, wc = w & 1;  // wave's 64x64 sub-tile
  const unsigned short* Abase = X + (size_t)ti * 128 * 512;
  const unsigned short* Bbase = X + (size_t)tj * 128 * 512;
  int lr = lane >> 3, lc = lane & 7;

  float thr = 0.f;
  if (MASK) {
    thr = 0.5f * decf(*dmax);
    uint4 z = make_uint4(0u, 0u, 0u, 0u);
    if (ti != tj) {  // mirror tile (rows ti, cols tj) never receives mask writes
#pragma unroll
      for (int q0 = 0; q0 < 4; ++q0) {
        int q = t + q0 * 256; int r = q >> 3, c4 = q & 7;
        *(uint4*)(ATm + (size_t)(ti * 128 + r) * NN + tj * 128 + c4 * 16) = z;
      }
    }
    if (tileMin[blockIdx.x] >= thr) {  // no element can pass -> zero tile, skip GEMM
#pragma unroll
      for (int q0 = 0; q0 < 4; ++q0) {
        int q = t + q0 * 256; int r = q >> 3, c4 = q & 7;
        *(uint4*)(ATm + (size_t)(tj * 128 + r) * NN + ti * 128 + c4 * 16) = z;
      }
      return;
    }
  }

  auto stage = [&](int buf, int k0) {  // 8 DMAs per wave (4x A + 4x B)
#pragma unroll
    for (int i = 0; i < 4; ++i) {
      int q = w * 4 + i;
      int r = q * 8 + lr;
      int cs = lc ^ (r & 7);  // pre-swizzled source chunk
      __builtin_amdgcn_global_load_lds(
          (const __attribute__((address_space(1))) unsigned int*)(Abase + (size_t)r * 512 + k0 + cs * 8),
          (__attribute__((address_space(3))) unsigned int*)(&As[buf][q * 512]), 16, 0, 0);
      __builtin_amdgcn_global_load_lds(
          (const __attribute__((address_space(1))) unsigned int*)(Bbase + (size_t)r * 512 + k0 + cs * 8),
          (__attribute__((address_space(3))) unsigned int*)(&Bs[buf][q * 512]), 16, 0, 0);
    }
  };

  stage(0, 0);  // 8 outstanding

  f32x4 acc[4][4] = {};
  int rl = lane & 15, kg = lane >> 4;
  for (int step = 0; step < 8; ++step) {
    int cur = step & 1;
    if (step < 7) {
      stage(cur ^ 1, (step + 1) * BK);  // +8 in flight (16 total)
      asm volatile("s_waitcnt vmcnt(8)" ::: "memory");  // cur's 8 retired (in-order)
    } else {
      asm volatile("s_waitcnt vmcnt(0)" ::: "memory");
    }
    __builtin_amdgcn_sched_barrier(0);
    __builtin_amdgcn_s_barrier();  // all waves' cur panel visible
    __builtin_amdgcn_s_setprio(1);
#pragma unroll
    for (int ks = 0; ks < 2; ++ks) {
      bf16x8 af[4], bq[4];
#pragma unroll
      for (int f = 0; f < 4; ++f) {
        int rA = wr * 64 + f * 16 + rl;
        af[f] = *(const bf16x8*)(&As[cur][rA * BK + (((ks * 4 + kg) ^ (rA & 7)) << 3)]);
        int rB = wc * 64 + f * 16 + rl;
        bq[f] = *(const bf16x8*)(&Bs[cur][rB * BK + (((ks * 4 + kg) ^ (rB & 7)) << 3)]);
      }
#pragma unroll
      for (int a = 0; a < 4; ++a)
#pragma unroll
        for (int b = 0; b < 4; ++b)
          acc[a][b] = __builtin_amdgcn_mfma_f32_16x16x32_bf16(af[a], bq[b], acc[a][b], 0, 0, 0);
    }
    __builtin_amdgcn_s_setprio(0);
    __builtin_amdgcn_sched_barrier(0);  // pin ds_reads before the reuse barrier
    __builtin_amdgcn_s_barrier();       // all reads of cur done before its overwrite
  }
  // C/D layout: col = lane&15, row = (lane>>4)*4 + reg   [m89/m91 verified]
  int rbase = ti * 128 + wr * 64 + ((lane >> 4) << 2);
  int cbase = tj * 128 + wc * 64 + (lane & 15);
  if (!MASK) {
    float lm = -1e30f, lmin = 1e30f;
#pragma unroll
    for (int a = 0; a < 4; ++a) {
      float si[4];
#pragma unroll
      for (int r = 0; r < 4; ++r) si[r] = sqv[rbase + a * 16 + r];
#pragma unroll
      for (int b = 0; b < 4; ++b) {
        int gj = cbase + b * 16;
        float sj = sqv[gj];
#pragma unroll
        for (int r = 0; r < 4; ++r) {
          float d2v = si[r] - 2.f * acc[a][b][r] + sj;
          lm = fmaxf(lm, d2v);
          if (rbase + a * 16 + r < gj) lmin = fminf(lmin, d2v);
        }
      }
    }
#pragma unroll
    for (int o = 32; o > 0; o >>= 1) {
      lm = fmaxf(lm, __shfl_xor(lm, o));
      lmin = fminf(lmin, __shfl_xor(lmin, o));
    }
    if (lane == 0) { wmax[w] = lm; wmin[w] = lmin; }
    __syncthreads();
    if (t == 0) {
      atomicMax(dmax, encf(fmaxf(fmaxf(wmax[0], wmax[1]), fmaxf(wmax[2], wmax[3]))));
      tileMin[blockIdx.x] = fminf(fminf(wmin[0], wmin[1]), fminf(wmin[2], wmin[3]));
    }
  } else {
#pragma unroll
    for (int b = 0; b < 4; ++b) {
      int gj = cbase + b * 16;
      float sj = sqv[gj];
      int rowcnt = 0;
#pragma unroll
      for (int a = 0; a < 4; ++a) {
        int gi0 = rbase + a * 16;
        union { unsigned char c[4]; unsigned u; } m4;
#pragma unroll
        for (int r = 0; r < 4; ++r) {
          float d2v = sqv[gi0 + r] - 2.f * acc[a][b][r] + sj;
          unsigned char mv = (d2v < thr && (gi0 + r) < gj) ? 1 : 0;
          m4.c[r] = mv; rowcnt += mv;
        }
        *(unsigned*)(ATm + (size_t)gj * NN + gi0) = m4.u;  // AT[j][i..i+3]
      }
      if (rowcnt) atomicAdd(&deg[gj], rowcnt);
    }
  }
}

// ---------- fp32 GEMM + row scale (R17-proven 32x64 tile, float2/float4 stages) ----------
__global__ __launch_bounds__(256) void k_gemm(const float* A, const float* B, const int* deg,
                                              float* C, int M, int N, int K) {
  __shared__ float Ast[16][34];
  __shared__ float Bs[16][64];
  int t = threadIdx.x, tx = t & 15, ty = t >> 4;
  int nbx = N >> 6;
  int total = gridDim.x;
  int bid0 = blockIdx.x;
  int bid = (bid0 & 7) * (total >> 3) + (bid0 >> 3);  // bijective: total%8==0
  int m0 = (bid / nbx) * 32, n0 = (bid % nbx) * 64;
  int ar = t >> 3, ac = (t * 2) & 15;   // A stage: 2 floats/thread (transposed write)
  int br = t >> 4, bc = (t & 15) * 4;   // B stage: 4 floats/thread
  float2 ra = *(const float2*)(A + (size_t)(m0 + ar) * K + ac);
  float4 rb = *(const float4*)(B + (size_t)br * N + n0 + bc);
  float acc[2][4] = {};
  for (int k0 = 0; k0 < K; k0 += 16) {
    Ast[ac][ar] = ra.x; Ast[ac + 1][ar] = ra.y;
    *(float4*)(&Bs[br][bc]) = rb;
    __syncthreads();
    if (k0 + 16 < K) {  // prefetch next panel (overlaps compute)
      ra = *(const float2*)(A + (size_t)(m0 + ar) * K + k0 + 16 + ac);
      rb = *(const float4*)(B + (size_t)(k0 + 16 + br) * N + n0 + bc);
    }
#pragma unroll
    for (int kk = 0; kk < 16; ++kk) {
      float2 av = *(const float2*)(&Ast[kk][ty * 2]);
      float4 bv = *(const float4*)(&Bs[kk][tx * 4]);
      acc[0][0] = fmaf(av.x, bv.x, acc[0][0]);
      acc[0][1] = fmaf(av.x, bv.y, acc[0][1]);
      acc[0][2] = fmaf(av.x, bv.z, acc[0][2]);
      acc[0][3] = fmaf(av.x, bv.w, acc[0][3]);
      acc[1][0] = fmaf(av.y, bv.x, acc[1][0]);
      acc[1][1] = fmaf(av.y, bv.y, acc[1][1]);
      acc[1][2] = fmaf(av.y, bv.z, acc[1][2]);
      acc[1][3] = fmaf(av.y, bv.w, acc[1][3]);
    }
    __syncthreads();
  }
#pragma unroll
  for (int a = 0; a < 2; ++a) {
    float dv = 1.f / sqrtf((float)(1 + deg[m0 + ty * 2 + a]));
#pragma unroll
    for (int b2 = 0; b2 < 4; ++b2)
      C[(size_t)(m0 + ty * 2 + a) * N + n0 + tx * 4 + b2] = acc[a][b2] * dv;
  }
}

// ---------- fused: xg row + relu + y2 + (deg==0) score ----------
__global__ __launch_bounds__(256) void k_agg(const float* y, const unsigned char* ATm,
                                             const int* deg, const float* bias,
                                             const float* Wpool, const float* bp,
                                             float* out, float* y2, float* score, int n) {
  __shared__ unsigned char mrow[256];
  __shared__ int s_any;
  __shared__ float wred[4];
  int j = blockIdx.x, t = threadIdx.x, lane = t & 63, w = t >> 6;
  int dg = deg[j];
  float dj = 1.f / sqrtf((float)(1 + dg));
  float acc = y[(size_t)j * 256 + t];
  if (dg != 0) {
    for (int i0 = 0; i0 < n; i0 += 256) {
      if (t == 0) s_any = 0;
      __syncthreads();
      unsigned char m = ATm[(size_t)j * n + i0 + t];
      mrow[t] = m;
      if (m) s_any = 1;
      __syncthreads();
      if (s_any) {
        for (int u = 0; u < 256; ++u)
          if (mrow[u]) acc += y[(size_t)(i0 + u) * 256 + t];
      }
      __syncthreads();
    }
  }
  float o = fmaxf(dj * acc + bias[t], 0.f);
  out[(size_t)j * 256 + t] = o;
  float rv = o * Wpool[t];
#pragma unroll
  for (int os = 32; os > 0; os >>= 1) rv += __shfl_xor(rv, os);
  if (lane == 0) wred[w] = rv;
  __syncthreads();
  if (t == 0) {
    float yy = dj * (wred[0] + wred[1] + wred[2] + wred[3]);
    y2[j] = yy;
    if (dg == 0) score[j] = tanhf(dj * yy + bp[0]);  // s=0: identical to scorek
  }
}

// ---------- score[j] for deg>0 rows only (deg==0 written by k_agg) ----------
__global__ __launch_bounds__(256) void k_scorek(const float* y2, const unsigned char* ATm,
                                                const int* deg, const float* bp,
                                                float* score, int n) {
  int w = threadIdx.x >> 6, lane = threadIdx.x & 63;
  int j = blockIdx.x * 4 + w;
  if (j >= n) return;
  int dg = deg[j];
  if (dg == 0) return;  // agg already wrote score[j]
  float dj = 1.f / sqrtf((float)(1 + dg));
  float s = 0.f;
  const uint4* row = (const uint4*)(ATm + (size_t)j * n);
  for (int p = lane; p < n / 16; p += 64) {
    uint4 v = row[p];
    if (v.x | v.y | v.z | v.w) {
      int base = p * 16;
#pragma unroll
      for (int q = 0; q < 4; ++q) {
        unsigned u = (&v.x)[q];
#pragma unroll
        for (int b2 = 0; b2 < 4; ++b2)
          if ((u >> (8 * b2)) & 0xffu) s += y2[base + q * 4 + b2];
      }
    }
  }
  for (int sh = 32; sh > 0; sh >>= 1) s += __shfl_down(s, sh);
  if (lane == 0) score[j] = tanhf(dj * (y2[j] + s) + bp[0]);
}

// ---------- radix-select top-k (exact PyG set semantics; output in index order) ----------
__global__ __launch_bounds__(1024) void k_topsel(const float* score, int n, int k,
                                                 int* perm, float* vals) {
  __shared__ unsigned keys[4096];
  __shared__ unsigned hist[256];
  __shared__ unsigned s_state[2];  // [0]=prefix(cutoff), [1]=need(ties to take)
  __shared__ unsigned woff[16];
  int t = threadIdx.x, lane = t & 63, w = t >> 6;
  for (int i = t; i < 4096; i += 1024) keys[i] = (i < n) ? encf(score[i]) : 0u;
  if (t == 0) { s_state[0] = 0u; s_state[1] = (unsigned)k; }
  __syncthreads();

  for (int pass = 0; pass < 4; ++pass) {
    int shift = 24 - pass * 8;
    if (t < 256) hist[t] = 0u;
    __syncthreads();
    unsigned prefix = s_state[0];
    unsigned need = s_state[1];
    unsigned pmask = pass ? (0xFFFFFFFFu << (shift + 8)) : 0u;
    for (int i = t; i < n; i += 1024) {
      unsigned kk = keys[i];
      if ((kk & pmask) == prefix) atomicAdd(&hist[(kk >> shift) & 255u], 1u);
    }
    __syncthreads();
    if (w == 0) {
      unsigned h[4], suf[4];
#pragma unroll
      for (int r = 0; r < 4; ++r) h[r] = hist[lane * 4 + r];
      suf[3] = h[3]; suf[2] = h[2] + suf[3]; suf[1] = h[1] + suf[2]; suf[0] = h[0] + suf[1];
      unsigned lsum = suf[0];
      unsigned s = lsum;
#pragma unroll
      for (int off = 1; off < 64; off <<= 1) {
        unsigned o = __shfl_down(s, off);
        if (lane + off < 64) s += o;
      }
      unsigned Hl = s - lsum;
      int cand = -1; unsigned cumAt = 0, histAt = 0;
#pragma unroll
      for (int r = 0; r < 4; ++r) {
        unsigned c = Hl + suf[r];
        if (c >= need) { cand = lane * 4 + r; cumAt = c; histAt = h[r]; }
      }
      int gmax = cand;
#pragma unroll
      for (int off = 32; off > 0; off >>= 1) {
        int o = __shfl_xor(gmax, off);
        gmax = o > gmax ? o : gmax;
      }
      if (cand == gmax && cand >= 0) {
        s_state[0] = prefix | ((unsigned)cand << shift);
        s_state[1] = need - (cumAt - histAt);
      }
    }
    __syncthreads();
  }
  unsigned cutoff = s_state[0];
  unsigned tcount = s_state[1];
  unsigned G = (unsigned)k - tcount;

  int i0 = t * 4;
  unsigned loc[4], cnt = 0;
#pragma unroll
  for (int r = 0; r < 4; ++r) {
    unsigned kk = keys[i0 + r];
    unsigned g = (kk > cutoff) ? 1u : 0u;
    unsigned e = (kk == cutoff) ? 1u : 0u;
    loc[r] = cnt;
    cnt += (g << 16) | e;
  }
  unsigned inc = cnt;
#pragma unroll
  for (int off = 1; off < 64; off <<= 1) {
    unsigned o = __shfl_up(inc, off);
    if (lane >= off) inc += o;
  }
  if (lane == 63) woff[w] = inc;
  __syncthreads();
  if (t == 0) {
    unsigned run = 0;
    for (int q = 0; q < 16; ++q) { unsigned v = woff[q]; woff[q] = run; run += v; }
  }
  __syncthreads();
  unsigned base = woff[w] + (inc - cnt);
#pragma unroll
  for (int r = 0; r < 4; ++r) {
    unsigned kk = keys[i0 + r];
    unsigned p = base + loc[r];
    if (kk > cutoff) {
      unsigned pos = p >> 16;
      perm[pos] = i0 + r; vals[pos] = decf(kk);
    } else if (kk == cutoff) {
      unsigned pe = p & 0xffffu;
      if (pe < tcount) { perm[G + pe] = i0 + r; vals[G + pe] = decf(kk); }
    }
  }
}

// ---------- merged pool: blocks [0,RB) gather+readout partials; [RB,RB+kn) gatherA ----------
__global__ __launch_bounds__(256) void k_pool(const float* xg, const int* perm, const float* vals,
                                              float* xp, float* pmax, float* psum, int k,
                                              const unsigned char* ATold, const int* degCur,
                                              unsigned char* ATnew, int* degNext, int nold) {
  __shared__ int sperm[4096];
  __shared__ int redi[256];
  int b = blockIdx.x, t = threadIdx.x;
  if (b < RB) {  // gather xp rows + per-block max/sum partials
    float m = -1e30f, s = 0.f;
    for (int r = b; r < k; r += RB) {
      float v = xg[(size_t)perm[r] * 256 + t] * vals[r];
      if (xp) xp[(size_t)r * 256 + t] = v;
      m = fmaxf(m, v); s += v;
    }
    pmax[b * 256 + t] = m; psum[b * 256 + t] = s;
    return;
  }
  // gatherA: ATnew[c][r] = ATold[perm[c]][perm[r]], degNext[c] = row count
  int c = b - RB;
  int src = perm[c];
  if (degCur[src] == 0) {  // empty source row: never read (deg gating) -> no writes
    if (t == 0) degNext[c] = 0;
    return;
  }
  for (int r = t; r < k; r += 256) sperm[r] = perm[r];
  __syncthreads();
  unsigned char* orow = ATnew + (size_t)c * k;
  const unsigned char* row = ATold + (size_t)src * nold;
  int cnt = 0;
  for (int r = t; r < k; r += 256) { unsigned char v = row[sperm[r]]; orow[r] = v; cnt += v; }
  redi[t] = cnt; __syncthreads();
  for (int s = 128; s > 0; s >>= 1) { if (t < s) redi[t] += redi[t + s]; __syncthreads(); }
  if (t == 0) degNext[c] = redi[0];
}

// ---------- single deferred readout finalize for all 3 layers ----------
__global__ void k_rfin3(const float* pm0, const float* ps0, int k0,
                        const float* pm1, const float* ps1, int k1,
                        const float* pm2, const float* ps2, int k2, float* out) {
  int t = threadIdx.x;
  float m0 = -1e30f, s0 = 0.f, m1 = -1e30f, s1 = 0.f, m2 = -1e30f, s2 = 0.f;
  for (int q = 0; q < RB; ++q) {
    m0 = fmaxf(m0, pm0[q * 256 + t]); s0 += ps0[q * 256 + t];
    m1 = fmaxf(m1, pm1[q * 256 + t]); s1 += ps1[q * 256 + t];
    m2 = fmaxf(m2, pm2[q * 256 + t]); s2 += ps2[q * 256 + t];
  }
  out[t] = m0 + m1 + m2;  // same left-assoc order as per-layer +=
  out[256 + t] = s0 / (float)k0 + s1 / (float)k1 + s2 / (float)k2;
}

// ---------- host-side layer driver ----------
static void run_layer(hipStream_t stream, const float* x_in, int n, int inC,
                      const float* W, const float* b, const float* Wpool, const float* bpool,
                      int k, const unsigned char* ATcur, unsigned char* ATnext,
                      const int* degCur, int* degNext,
                      float* ybuf, float* xg, float* xp, float* y2,
                      float* score, int* perm, float* vals, float* pmax, float* psum) {
  k_gemm<<<(n / 32) * 4, 256, 0, stream>>>(x_in, W, degCur, ybuf, n, 256, inC);
  k_agg<<<n, 256, 0, stream>>>(ybuf, ATcur, degCur, b, Wpool, bpool, xg, y2, score, n);
  k_scorek<<<n / 4, 256, 0, stream>>>(y2, ATcur, degCur, bpool, score, n);
  k_topsel<<<1, 1024, 0, stream>>>(score, n, k, perm, vals);
  int grid = RB + (ATnext ? k : 0);
  k_pool<<<grid, 256, 0, stream>>>(xg, perm, vals, ATnext ? xp : nullptr, pmax, psum, k,
                                   ATcur, degCur, ATnext, degNext, n);
}

extern "C" void kernel_launch(void* const* d_in, const int* in_sizes, int n_in,
                              void* d_out, int out_size, void* d_ws, size_t ws_size,
                              hipStream_t stream) {
  const float* feature = (const float*)d_in[0];
  const float* img     = (const float*)d_in[1];
  const float* Wp      = (const float*)d_in[2];
  const float* bp      = (const float*)d_in[3];
  const float* ln_f_g  = (const float*)d_in[4];
  const float* ln_f_b  = (const float*)d_in[5];
  const float* ln_p_g  = (const float*)d_in[6];
  const float* ln_p_b  = (const float*)d_in[7];
  const float* W1 = (const float*)d_in[8];   const float* b1 = (const float*)d_in[9];
  const float* Wpool1 = (const float*)d_in[10]; const float* bpool1 = (const float*)d_in[11];
  const float* W2 = (const float*)d_in[12];  const float* b2 = (const float*)d_in[13];
  const float* Wpool2 = (const float*)d_in[14]; const float* bpool2 = (const float*)d_in[15];
  const float* W3 = (const float*)d_in[16];  const float* b3 = (const float*)d_in[17];
  const float* Wpool3 = (const float*)d_in[18]; const float* bpool3 = (const float*)d_in[19];
  float* out = (float*)d_out;
  (void)in_sizes; (void)n_in; (void)out_size; (void)ws_size;

  char* w = (char*)d_ws;
  size_t off = 0;
  auto alloc = [&](size_t bytes) -> char* {
    off = (off + 255) & ~(size_t)255;
    char* p = w + off;
    off += bytes;
    return p;
  };
  float* pos0 = (float*)alloc((size_t)NN * 12 * 4);
  float* pos1 = (float*)alloc((size_t)NN * 12 * 4);
  float* x0   = (float*)alloc((size_t)NN * 512 * 4);
  unsigned short* x0h = (unsigned short*)alloc((size_t)NN * 512 * 2);
  float* sqv  = (float*)alloc((size_t)NN * 4);
  unsigned* dmax = (unsigned*)alloc(4);
  float* tileMin = (float*)alloc(528 * 4);
  int* degA = (int*)alloc((size_t)NN * 4);
  int* degB = (int*)alloc((size_t)NN * 4);
  float* ybuf = (float*)alloc((size_t)NN * 256 * 4);
  float* xg   = (float*)alloc((size_t)NN * 256 * 4);
  float* xp   = (float*)alloc((size_t)NN * 256 * 4);
  float* y2   = (float*)alloc((size_t)NN * 4);
  float* score= (float*)alloc((size_t)NN * 4);
  int*   perm = (int*)alloc((size_t)NN * 4);
  float* vals = (float*)alloc((size_t)NN * 4);
  float* pmax0 = (float*)alloc(RB * 256 * 4);
  float* psum0 = (float*)alloc(RB * 256 * 4);
  float* pmax1 = (float*)alloc(RB * 256 * 4);
  float* psum1 = (float*)alloc(RB * 256 * 4);
  float* pmax2 = (float*)alloc(RB * 256 * 4);
  float* psum2 = (float*)alloc(RB * 256 * 4);
  unsigned char* ATa = (unsigned char*)alloc((size_t)NN * NN);
  unsigned char* ATb = (unsigned char*)alloc((size_t)3072 * 3072);

  // preamble (init fused into k_pos; lnx zeroes degA)
  k_pos<<<(NN * 12 + 255) / 256, 256, 0, stream>>>(img, Wp, bp, pos0, dmax);
  k_attn3<<<NN / 8, 256, 0, stream>>>(pos0, pos1);
  k_lnx<<<NN, 256, 0, stream>>>(feature, ln_f_g, ln_f_b, pos1, ln_p_g, ln_p_b,
                                x0, x0h, sqv, degA);

  // edge construction via MFMA: max+tileMin pass, then pruned mask pass (+deg atomics)
  const int NT = NN / 128, TT = NT * (NT + 1) / 2;  // 32, 528
  k_d2m<false><<<TT, 256, 0, stream>>>(x0h, sqv, dmax, tileMin, nullptr, nullptr);
  k_d2m<true><<<TT, 256, 0, stream>>>(x0h, sqv, dmax, tileMin, ATa, degA);

  // three GCN + SAGPool + readout layers (readout finalize deferred to k_rfin3)
  run_layer(stream, x0, 4096, 512, W1, b1, Wpool1, bpool1, 3072, ATa, ATb, degA, degB,
            ybuf, xg, xp, y2, score, perm, vals, pmax0, psum0);
  run_layer(stream, xp, 3072, 256, W2, b2, Wpool2, bpool2, 2304, ATb, ATa, degB, degA,
            ybuf, xg, xp, y2, score, perm, vals, pmax1, psum1);
  run_layer(stream, xp, 2304, 256, W3, b3, Wpool3, bpool3, 1728, ATa, nullptr, degA, nullptr,
            ybuf, xg, xp, y2, score, perm, vals, pmax2, psum2);
  k_rfin3<<<1, 256, 0, stream>>>(pmax0, psum0, 3072, pmax1, psum1, 2304,
                                 pmax2, psum2, 1728, out);
}

// Round 20
// 214.495 us; speedup vs baseline: 1.0276x; 1.0037x over previous
//
#include <hip/hip_runtime.h>
#include <math.h>

#define NN 4096
#define RB 128  // readout stage-1 blocks

typedef __attribute__((ext_vector_type(8))) short bf16x8;
typedef __attribute__((ext_vector_type(4))) float f32x4;

// ---------- helpers ----------
__device__ __forceinline__ unsigned encf(float f) {
  unsigned u = __float_as_uint(f);
  return (u & 0x80000000u) ? ~u : (u | 0x80000000u);
}
__device__ __forceinline__ float decf(unsigned u) {
  return __uint_as_float((u & 0x80000000u) ? (u ^ 0x80000000u) : ~u);
}
__device__ __forceinline__ unsigned short f2bf(float f) {
  unsigned u = __float_as_uint(f);
  return (unsigned short)((u + 0x7fffu + ((u >> 16) & 1u)) >> 16);
}

// ---------- fused pos-embed + attention (d=12), LDS-tiled keys ----------
// pos[j] = img[j]@Wp + bp computed on the fly (same fma order as the old k_pos ->
// bitwise-identical). Branch-free softmax (scores tiny; exp safe without max-shift).
__global__ __launch_bounds__(256) void k_attn3(const float* img, const float* Wp,
                                               const float* bp, float* out) {
  __shared__ float sp[12][256];
  __shared__ float wp[72];
  __shared__ float bpd[12];
  int t = threadIdx.x, lane = t & 63, w = t >> 6;
  int ib = blockIdx.x * 8 + w * 2;  // 2 rows per wave, 8 per block
  if (t < 72) wp[t] = Wp[t];
  if (t < 12) bpd[t] = bp[t];
  __syncthreads();
  float pi[2][12];
#pragma unroll
  for (int r = 0; r < 2; ++r) {
    float iv[6];
#pragma unroll
    for (int k = 0; k < 6; ++k) iv[k] = img[(ib + r) * 6 + k];
#pragma unroll
    for (int d = 0; d < 12; ++d) {
      float s = bpd[d];
#pragma unroll
      for (int k = 0; k < 6; ++k) s += iv[k] * wp[k * 12 + d];
      pi[r][d] = s * 0.28867513459481287f;
    }
  }
  float sl[2] = {0.f, 0.f};
  float acc[2][12] = {};
  for (int kt = 0; kt < NN; kt += 256) {
    __syncthreads();  // previous tile fully consumed
    int j = kt + t;
    float iv[6];
#pragma unroll
    for (int k = 0; k < 6; ++k) iv[k] = img[j * 6 + k];
#pragma unroll
    for (int d = 0; d < 12; ++d) {
      float s = bpd[d];
#pragma unroll
      for (int k = 0; k < 6; ++k) s += iv[k] * wp[k * 12 + d];
      sp[d][t] = s;
    }
    __syncthreads();
#pragma unroll
    for (int q = 0; q < 4; ++q) {
      int jj = q * 64 + lane;
      float pj[12];
#pragma unroll
      for (int d = 0; d < 12; ++d) pj[d] = sp[d][jj];
#pragma unroll
      for (int r = 0; r < 2; ++r) {
        float s = 0.f;
#pragma unroll
        for (int d = 0; d < 12; ++d) s = fmaf(pi[r][d], pj[d], s);
        float e = __expf(s);
        sl[r] += e;
#pragma unroll
        for (int d = 0; d < 12; ++d) acc[r][d] = fmaf(e, pj[d], acc[r][d]);
      }
    }
  }
#pragma unroll
  for (int r = 0; r < 2; ++r) {
    float s = sl[r];
#pragma unroll
    for (int o = 32; o > 0; o >>= 1) s += __shfl_xor(s, o);
    float ad[12];
#pragma unroll
    for (int d = 0; d < 12; ++d) {
      ad[d] = acc[r][d];
#pragma unroll
      for (int o = 32; o > 0; o >>= 1) ad[d] += __shfl_xor(ad[d], o);
    }
    if (lane == 0) {
      float inv = 1.f / s;
#pragma unroll
      for (int d = 0; d < 12; ++d) out[(ib + r) * 12 + d] = ad[d] * inv;
    }
  }
}

// ---------- fused layernorms + sumsq + bf16 convert (+ init dmax/rowMin/degA) ----------
__global__ __launch_bounds__(256) void k_lnx(const float* f, const float* g, const float* b,
                                             const float* p, const float* pg, const float* pb,
                                             float* x0, unsigned short* x0h, float* sqv,
                                             int* degA, unsigned* dmax, unsigned* rowMin) {
  __shared__ float row[512];
  __shared__ float wrA[4], wrB[4], wrC[4];
  int i = blockIdx.x, t = threadIdx.x, lane = t & 63, w = t >> 6;
  if (t == 0) degA[i] = 0;
  if (i == 0) {
    if (t == 0) *dmax = 0u;
    if (t < 32) rowMin[t] = 0xFFFFFFFFu;
  }
  float v1 = f[i * 500 + t];
  float v2 = (t < 244) ? f[i * 500 + 256 + t] : 0.f;
  float part = v1 + v2;
#pragma unroll
  for (int o = 32; o > 0; o >>= 1) part += __shfl_xor(part, o);
  if (lane == 0) wrA[w] = part;
  __syncthreads();
  float m = (wrA[0] + wrA[1] + wrA[2] + wrA[3]) * (1.f / 500.f);
  float d1 = v1 - m, d2 = v2 - m;
  float pvv = d1 * d1 + ((t < 244) ? d2 * d2 : 0.f);
#pragma unroll
  for (int o = 32; o > 0; o >>= 1) pvv += __shfl_xor(pvv, o);
  if (lane == 0) wrB[w] = pvv;
  __syncthreads();
  float scale = 1.f / sqrtf((wrB[0] + wrB[1] + wrB[2] + wrB[3]) * (1.f / 500.f) + 1e-5f);
  row[t] = d1 * scale * g[t] + b[t];
  if (t < 244) row[256 + t] = d2 * scale * g[256 + t] + b[256 + t];
  if (t >= 244) {  // threads 244..255 handle the 12-wide pos layernorm
    int tt = t - 244;
    float pv[12], pm = 0.f;
#pragma unroll
    for (int d = 0; d < 12; ++d) { pv[d] = p[i * 12 + d]; pm += pv[d]; }
    pm *= (1.f / 12.f);
    float pvar = 0.f;
#pragma unroll
    for (int d = 0; d < 12; ++d) { float dd = pv[d] - pm; pvar += dd * dd; }
    pvar *= (1.f / 12.f);
    float ps = 1.f / sqrtf(pvar + 1e-5f);
    row[500 + tt] = (pv[tt] - pm) * ps * pg[tt] + pb[tt];
  }
  __syncthreads();
  float a = row[t], c = row[256 + t];
  float sq = a * a + c * c;
#pragma unroll
  for (int o = 32; o > 0; o >>= 1) sq += __shfl_xor(sq, o);
  if (lane == 0) wrC[w] = sq;
  __syncthreads();
  if (t == 0) sqv[i] = wrC[0] + wrC[1] + wrC[2] + wrC[3];
  x0[(size_t)i * 512 + t] = a;
  x0[(size_t)i * 512 + 256 + t] = c;
  x0h[(size_t)i * 512 + t] = f2bf(a);
  x0h[(size_t)i * 512 + 256 + t] = f2bf(c);
}

// ---------- MFMA d2 tiles (128x128, upper tile pairs): max / mask pass ----------
// T4 pipeline: double-buffered LDS; counted vmcnt(8), sched_barrier(0), raw s_barrier,
// T5 setprio around MFMA. Pass A: global max + per-tile min over gi<gj + rowMin[J] =
// min tileMin over pairs (.,J) (atomicMin on encf bits). Pass B: zero/mask writes to a
// row-block only if it's ALIVE (rowMin < encf(thr)); dead rows have deg==0 and are
// never read by any consumer (all deg-gated) -> exact for every input.
#define BK 64
template <bool MASK>
__global__ __launch_bounds__(256) void k_d2m(const unsigned short* X, const float* sqv,
                                             unsigned* dmax, float* tileMin, unsigned* rowMin,
                                             unsigned char* ATm, int* deg) {
  __shared__ unsigned short As[2][128 * BK];
  __shared__ unsigned short Bs[2][128 * BK];
  __shared__ float wmax[4], wmin[4];
  const int NT = NN / 128;
  int bid0 = blockIdx.x;
  int bid = (bid0 & 7) * 66 + (bid0 >> 3);  // 528 total, bijective
  int ti = 0, rem = bid;
  while (rem >= NT - ti) { rem -= NT - ti; ++ti; }
  int tj = ti + rem;
  int t = threadIdx.x, lane = t & 63, w = t >> 6;
  int wr = w >> 1, wc = w & 1;  // wave's 64x64 sub-tile
  const unsigned short* Abase = X + (size_t)ti * 128 * 512;
  const unsigned short* Bbase = X + (size_t)tj * 128 * 512;
  int lr = lane >> 3, lc = lane & 7;

  float thr = 0.f;
  if (MASK) {
    thr = 0.5f * decf(*dmax);
    unsigned eth = encf(thr);
    uint4 z = make_uint4(0u, 0u, 0u, 0u);
    if (ti != tj && rowMin[ti] < eth) {  // mirror rows (ti-block) alive -> zero them
#pragma unroll
      for (int q0 = 0; q0 < 4; ++q0) {
        int q = t + q0 * 256; int r = q >> 3, c4 = q & 7;
        *(uint4*)(ATm + (size_t)(ti * 128 + r) * NN + tj * 128 + c4 * 16) = z;
      }
    }
    if (tileMin[blockIdx.x] >= thr) {  // tile pruned: no bits here
      if (rowMin[tj] < eth) {  // target rows alive elsewhere -> need zero coverage
#pragma unroll
        for (int q0 = 0; q0 < 4; ++q0) {
          int q = t + q0 * 256; int r = q >> 3, c4 = q & 7;
          *(uint4*)(ATm + (size_t)(tj * 128 + r) * NN + ti * 128 + c4 * 16) = z;
        }
      }
      return;
    }
  }

  auto stage = [&](int buf, int k0) {  // 8 DMAs per wave (4x A + 4x B)
#pragma unroll
    for (int i = 0; i < 4; ++i) {
      int q = w * 4 + i;
      int r = q * 8 + lr;
      int cs = lc ^ (r & 7);  // pre-swizzled source chunk
      __builtin_amdgcn_global_load_lds(
          (const __attribute__((address_space(1))) unsigned int*)(Abase + (size_t)r * 512 + k0 + cs * 8),
          (__attribute__((address_space(3))) unsigned int*)(&As[buf][q * 512]), 16, 0, 0);
      __builtin_amdgcn_global_load_lds(
          (const __attribute__((address_space(1))) unsigned int*)(Bbase + (size_t)r * 512 + k0 + cs * 8),
          (__attribute__((address_space(3))) unsigned int*)(&Bs[buf][q * 512]), 16, 0, 0);
    }
  };

  stage(0, 0);  // 8 outstanding

  f32x4 acc[4][4] = {};
  int rl = lane & 15, kg = lane >> 4;
  for (int step = 0; step < 8; ++step) {
    int cur = step & 1;
    if (step < 7) {
      stage(cur ^ 1, (step + 1) * BK);  // +8 in flight (16 total)
      asm volatile("s_waitcnt vmcnt(8)" ::: "memory");  // cur's 8 retired (in-order)
    } else {
      asm volatile("s_waitcnt vmcnt(0)" ::: "memory");
    }
    __builtin_amdgcn_sched_barrier(0);
    __builtin_amdgcn_s_barrier();  // all waves' cur panel visible
    __builtin_amdgcn_s_setprio(1);
#pragma unroll
    for (int ks = 0; ks < 2; ++ks) {
      bf16x8 af[4], bq[4];
#pragma unroll
      for (int f = 0; f < 4; ++f) {
        int rA = wr * 64 + f * 16 + rl;
        af[f] = *(const bf16x8*)(&As[cur][rA * BK + (((ks * 4 + kg) ^ (rA & 7)) << 3)]);
        int rB = wc * 64 + f * 16 + rl;
        bq[f] = *(const bf16x8*)(&Bs[cur][rB * BK + (((ks * 4 + kg) ^ (rB & 7)) << 3)]);
      }
#pragma unroll
      for (int a = 0; a < 4; ++a)
#pragma unroll
        for (int b = 0; b < 4; ++b)
          acc[a][b] = __builtin_amdgcn_mfma_f32_16x16x32_bf16(af[a], bq[b], acc[a][b], 0, 0, 0);
    }
    __builtin_amdgcn_s_setprio(0);
    __builtin_amdgcn_sched_barrier(0);  // pin ds_reads before the reuse barrier
    __builtin_amdgcn_s_barrier();       // all reads of cur done before its overwrite
  }
  // C/D layout: col = lane&15, row = (lane>>4)*4 + reg   [m89/m91 verified]
  int rbase = ti * 128 + wr * 64 + ((lane >> 4) << 2);
  int cbase = tj * 128 + wc * 64 + (lane & 15);
  if (!MASK) {
    float lm = -1e30f, lmin = 1e30f;
#pragma unroll
    for (int a = 0; a < 4; ++a) {
      float si[4];
#pragma unroll
      for (int r = 0; r < 4; ++r) si[r] = sqv[rbase + a * 16 + r];
#pragma unroll
      for (int b = 0; b < 4; ++b) {
        int gj = cbase + b * 16;
        float sj = sqv[gj];
#pragma unroll
        for (int r = 0; r < 4; ++r) {
          float d2v = si[r] - 2.f * acc[a][b][r] + sj;
          lm = fmaxf(lm, d2v);
          if (rbase + a * 16 + r < gj) lmin = fminf(lmin, d2v);
        }
      }
    }
#pragma unroll
    for (int o = 32; o > 0; o >>= 1) {
      lm = fmaxf(lm, __shfl_xor(lm, o));
      lmin = fminf(lmin, __shfl_xor(lmin, o));
    }
    if (lane == 0) { wmax[w] = lm; wmin[w] = lmin; }
    __syncthreads();
    if (t == 0) {
      atomicMax(dmax, encf(fmaxf(fmaxf(wmax[0], wmax[1]), fmaxf(wmax[2], wmax[3]))));
      float tmin = fminf(fminf(wmin[0], wmin[1]), fminf(wmin[2], wmin[3]));
      tileMin[blockIdx.x] = tmin;
      atomicMin(&rowMin[tj], encf(tmin));
    }
  } else {
#pragma unroll
    for (int b = 0; b < 4; ++b) {
      int gj = cbase + b * 16;
      float sj = sqv[gj];
      int rowcnt = 0;
#pragma unroll
      for (int a = 0; a < 4; ++a) {
        int gi0 = rbase + a * 16;
        union { unsigned char c[4]; unsigned u; } m4;
#pragma unroll
        for (int r = 0; r < 4; ++r) {
          float d2v = sqv[gi0 + r] - 2.f * acc[a][b][r] + sj;
          unsigned char mv = (d2v < thr && (gi0 + r) < gj) ? 1 : 0;
          m4.c[r] = mv; rowcnt += mv;
        }
        *(unsigned*)(ATm + (size_t)gj * NN + gi0) = m4.u;  // AT[j][i..i+3]
      }
      if (rowcnt) atomicAdd(&deg[gj], rowcnt);
    }
  }
}

// ---------- fp32 GEMM + row scale (R17-proven 32x64 tile, float2/float4 stages) ----------
__global__ __launch_bounds__(256) void k_gemm(const float* A, const float* B, const int* deg,
                                              float* C, int M, int N, int K) {
  __shared__ float Ast[16][34];
  __shared__ float Bs[16][64];
  int t = threadIdx.x, tx = t & 15, ty = t >> 4;
  int nbx = N >> 6;
  int total = gridDim.x;
  int bid0 = blockIdx.x;
  int bid = (bid0 & 7) * (total >> 3) + (bid0 >> 3);  // bijective: total%8==0
  int m0 = (bid / nbx) * 32, n0 = (bid % nbx) * 64;
  int ar = t >> 3, ac = (t * 2) & 15;   // A stage: 2 floats/thread (transposed write)
  int br = t >> 4, bc = (t & 15) * 4;   // B stage: 4 floats/thread
  float2 ra = *(const float2*)(A + (size_t)(m0 + ar) * K + ac);
  float4 rb = *(const float4*)(B + (size_t)br * N + n0 + bc);
  float acc[2][4] = {};
  for (int k0 = 0; k0 < K; k0 += 16) {
    Ast[ac][ar] = ra.x; Ast[ac + 1][ar] = ra.y;
    *(float4*)(&Bs[br][bc]) = rb;
    __syncthreads();
    if (k0 + 16 < K) {  // prefetch next panel (overlaps compute)
      ra = *(const float2*)(A + (size_t)(m0 + ar) * K + k0 + 16 + ac);
      rb = *(const float4*)(B + (size_t)(k0 + 16 + br) * N + n0 + bc);
    }
#pragma unroll
    for (int kk = 0; kk < 16; ++kk) {
      float2 av = *(const float2*)(&Ast[kk][ty * 2]);
      float4 bv = *(const float4*)(&Bs[kk][tx * 4]);
      acc[0][0] = fmaf(av.x, bv.x, acc[0][0]);
      acc[0][1] = fmaf(av.x, bv.y, acc[0][1]);
      acc[0][2] = fmaf(av.x, bv.z, acc[0][2]);
      acc[0][3] = fmaf(av.x, bv.w, acc[0][3]);
      acc[1][0] = fmaf(av.y, bv.x, acc[1][0]);
      acc[1][1] = fmaf(av.y, bv.y, acc[1][1]);
      acc[1][2] = fmaf(av.y, bv.z, acc[1][2]);
      acc[1][3] = fmaf(av.y, bv.w, acc[1][3]);
    }
    __syncthreads();
  }
#pragma unroll
  for (int a = 0; a < 2; ++a) {
    float dv = 1.f / sqrtf((float)(1 + deg[m0 + ty * 2 + a]));
#pragma unroll
    for (int b2 = 0; b2 < 4; ++b2)
      C[(size_t)(m0 + ty * 2 + a) * N + n0 + tx * 4 + b2] = acc[a][b2] * dv;
  }
}

// ---------- fused: xg row + relu + y2 + (deg==0) score ----------
__global__ __launch_bounds__(256) void k_agg(const float* y, const unsigned char* ATm,
                                             const int* deg, const float* bias,
                                             const float* Wpool, const float* bp,
                                             float* out, float* y2, float* score, int n) {
  __shared__ unsigned char mrow[256];
  __shared__ int s_any;
  __shared__ float wred[4];
  int j = blockIdx.x, t = threadIdx.x, lane = t & 63, w = t >> 6;
  int dg = deg[j];
  float dj = 1.f / sqrtf((float)(1 + dg));
  float acc = y[(size_t)j * 256 + t];
  if (dg != 0) {
    for (int i0 = 0; i0 < n; i0 += 256) {
      if (t == 0) s_any = 0;
      __syncthreads();
      unsigned char m = ATm[(size_t)j * n + i0 + t];
      mrow[t] = m;
      if (m) s_any = 1;
      __syncthreads();
      if (s_any) {
        for (int u = 0; u < 256; ++u)
          if (mrow[u]) acc += y[(size_t)(i0 + u) * 256 + t];
      }
      __syncthreads();
    }
  }
  float o = fmaxf(dj * acc + bias[t], 0.f);
  out[(size_t)j * 256 + t] = o;
  float rv = o * Wpool[t];
#pragma unroll
  for (int os = 32; os > 0; os >>= 1) rv += __shfl_xor(rv, os);
  if (lane == 0) wred[w] = rv;
  __syncthreads();
  if (t == 0) {
    float yy = dj * (wred[0] + wred[1] + wred[2] + wred[3]);
    y2[j] = yy;
    if (dg == 0) score[j] = tanhf(dj * yy + bp[0]);  // s=0: identical to scorek
  }
}

// ---------- score[j] for deg>0 rows only (deg==0 written by k_agg) ----------
__global__ __launch_bounds__(256) void k_scorek(const float* y2, const unsigned char* ATm,
                                                const int* deg, const float* bp,
                                                float* score, int n) {
  int w = threadIdx.x >> 6, lane = threadIdx.x & 63;
  int j = blockIdx.x * 4 + w;
  if (j >= n) return;
  int dg = deg[j];
  if (dg == 0) return;  // agg already wrote score[j]
  float dj = 1.f / sqrtf((float)(1 + dg));
  float s = 0.f;
  const uint4* row = (const uint4*)(ATm + (size_t)j * n);
  for (int p = lane; p < n / 16; p += 64) {
    uint4 v = row[p];
    if (v.x | v.y | v.z | v.w) {
      int base = p * 16;
#pragma unroll
      for (int q = 0; q < 4; ++q) {
        unsigned u = (&v.x)[q];
#pragma unroll
        for (int b2 = 0; b2 < 4; ++b2)
          if ((u >> (8 * b2)) & 0xffu) s += y2[base + q * 4 + b2];
      }
    }
  }
  for (int sh = 32; sh > 0; sh >>= 1) s += __shfl_down(s, sh);
  if (lane == 0) score[j] = tanhf(dj * (y2[j] + s) + bp[0]);
}

// ---------- radix-select top-k (exact PyG set semantics; output in index order) ----------
__global__ __launch_bounds__(1024) void k_topsel(const float* score, int n, int k,
                                                 int* perm, float* vals) {
  __shared__ unsigned keys[4096];
  __shared__ unsigned hist[256];
  __shared__ unsigned s_state[2];  // [0]=prefix(cutoff), [1]=need(ties to take)
  __shared__ unsigned woff[16];
  int t = threadIdx.x, lane = t & 63, w = t >> 6;
  for (int i = t; i < 4096; i += 1024) keys[i] = (i < n) ? encf(score[i]) : 0u;
  if (t == 0) { s_state[0] = 0u; s_state[1] = (unsigned)k; }
  __syncthreads();

  for (int pass = 0; pass < 4; ++pass) {
    int shift = 24 - pass * 8;
    if (t < 256) hist[t] = 0u;
    __syncthreads();
    unsigned prefix = s_state[0];
    unsigned need = s_state[1];
    unsigned pmask = pass ? (0xFFFFFFFFu << (shift + 8)) : 0u;
    for (int i = t; i < n; i += 1024) {
      unsigned kk = keys[i];
      if ((kk & pmask) == prefix) atomicAdd(&hist[(kk >> shift) & 255u], 1u);
    }
    __syncthreads();
    if (w == 0) {
      unsigned h[4], suf[4];
#pragma unroll
      for (int r = 0; r < 4; ++r) h[r] = hist[lane * 4 + r];
      suf[3] = h[3]; suf[2] = h[2] + suf[3]; suf[1] = h[1] + suf[2]; suf[0] = h[0] + suf[1];
      unsigned lsum = suf[0];
      unsigned s = lsum;
#pragma unroll
      for (int off = 1; off < 64; off <<= 1) {
        unsigned o = __shfl_down(s, off);
        if (lane + off < 64) s += o;
      }
      unsigned Hl = s - lsum;
      int cand = -1; unsigned cumAt = 0, histAt = 0;
#pragma unroll
      for (int r = 0; r < 4; ++r) {
        unsigned c = Hl + suf[r];
        if (c >= need) { cand = lane * 4 + r; cumAt = c; histAt = h[r]; }
      }
      int gmax = cand;
#pragma unroll
      for (int off = 32; off > 0; off >>= 1) {
        int o = __shfl_xor(gmax, off);
        gmax = o > gmax ? o : gmax;
      }
      if (cand == gmax && cand >= 0) {
        s_state[0] = prefix | ((unsigned)cand << shift);
        s_state[1] = need - (cumAt - histAt);
      }
    }
    __syncthreads();
  }
  unsigned cutoff = s_state[0];
  unsigned tcount = s_state[1];
  unsigned G = (unsigned)k - tcount;

  int i0 = t * 4;
  unsigned loc[4], cnt = 0;
#pragma unroll
  for (int r = 0; r < 4; ++r) {
    unsigned kk = keys[i0 + r];
    unsigned g = (kk > cutoff) ? 1u : 0u;
    unsigned e = (kk == cutoff) ? 1u : 0u;
    loc[r] = cnt;
    cnt += (g << 16) | e;
  }
  unsigned inc = cnt;
#pragma unroll
  for (int off = 1; off < 64; off <<= 1) {
    unsigned o = __shfl_up(inc, off);
    if (lane >= off) inc += o;
  }
  if (lane == 63) woff[w] = inc;
  __syncthreads();
  if (t == 0) {
    unsigned run = 0;
    for (int q = 0; q < 16; ++q) { unsigned v = woff[q]; woff[q] = run; run += v; }
  }
  __syncthreads();
  unsigned base = woff[w] + (inc - cnt);
#pragma unroll
  for (int r = 0; r < 4; ++r) {
    unsigned kk = keys[i0 + r];
    unsigned p = base + loc[r];
    if (kk > cutoff) {
      unsigned pos = p >> 16;
      perm[pos] = i0 + r; vals[pos] = decf(kk);
    } else if (kk == cutoff) {
      unsigned pe = p & 0xffffu;
      if (pe < tcount) { perm[G + pe] = i0 + r; vals[G + pe] = decf(kk); }
    }
  }
}

// ---------- merged pool: blocks [0,RB) gather+readout partials; [RB,RB+kn) gatherA ----------
__global__ __launch_bounds__(256) void k_pool(const float* xg, const int* perm, const float* vals,
                                              float* xp, float* pmax, float* psum, int k,
                                              const unsigned char* ATold, const int* degCur,
                                              unsigned char* ATnew, int* degNext, int nold) {
  __shared__ int sperm[4096];
  __shared__ int redi[256];
  int b = blockIdx.x, t = threadIdx.x;
  if (b < RB) {  // gather xp rows + per-block max/sum partials
    float m = -1e30f, s = 0.f;
    for (int r = b; r < k; r += RB) {
      float v = xg[(size_t)perm[r] * 256 + t] * vals[r];
      if (xp) xp[(size_t)r * 256 + t] = v;
      m = fmaxf(m, v); s += v;
    }
    pmax[b * 256 + t] = m; psum[b * 256 + t] = s;
    return;
  }
  // gatherA: ATnew[c][r] = ATold[perm[c]][perm[r]], degNext[c] = row count
  int c = b - RB;
  int src = perm[c];
  if (degCur[src] == 0) {  // empty source row: never read (deg gating) -> no writes
    if (t == 0) degNext[c] = 0;
    return;
  }
  for (int r = t; r < k; r += 256) sperm[r] = perm[r];
  __syncthreads();
  unsigned char* orow = ATnew + (size_t)c * k;
  const unsigned char* row = ATold + (size_t)src * nold;
  int cnt = 0;
  for (int r = t; r < k; r += 256) { unsigned char v = row[sperm[r]]; orow[r] = v; cnt += v; }
  redi[t] = cnt; __syncthreads();
  for (int s = 128; s > 0; s >>= 1) { if (t < s) redi[t] += redi[t + s]; __syncthreads(); }
  if (t == 0) degNext[c] = redi[0];
}

// ---------- single deferred readout finalize for all 3 layers ----------
__global__ void k_rfin3(const float* pm0, const float* ps0, int k0,
                        const float* pm1, const float* ps1, int k1,
                        const float* pm2, const float* ps2, int k2, float* out) {
  int t = threadIdx.x;
  float m0 = -1e30f, s0 = 0.f, m1 = -1e30f, s1 = 0.f, m2 = -1e30f, s2 = 0.f;
  for (int q = 0; q < RB; ++q) {
    m0 = fmaxf(m0, pm0[q * 256 + t]); s0 += ps0[q * 256 + t];
    m1 = fmaxf(m1, pm1[q * 256 + t]); s1 += ps1[q * 256 + t];
    m2 = fmaxf(m2, pm2[q * 256 + t]); s2 += ps2[q * 256 + t];
  }
  out[t] = m0 + m1 + m2;  // same left-assoc order as per-layer +=
  out[256 + t] = s0 / (float)k0 + s1 / (float)k1 + s2 / (float)k2;
}

// ---------- host-side layer driver ----------
static void run_layer(hipStream_t stream, const float* x_in, int n, int inC,
                      const float* W, const float* b, const float* Wpool, const float* bpool,
                      int k, const unsigned char* ATcur, unsigned char* ATnext,
                      const int* degCur, int* degNext,
                      float* ybuf, float* xg, float* xp, float* y2,
                      float* score, int* perm, float* vals, float* pmax, float* psum) {
  k_gemm<<<(n / 32) * 4, 256, 0, stream>>>(x_in, W, degCur, ybuf, n, 256, inC);
  k_agg<<<n, 256, 0, stream>>>(ybuf, ATcur, degCur, b, Wpool, bpool, xg, y2, score, n);
  k_scorek<<<n / 4, 256, 0, stream>>>(y2, ATcur, degCur, bpool, score, n);
  k_topsel<<<1, 1024, 0, stream>>>(score, n, k, perm, vals);
  int grid = RB + (ATnext ? k : 0);
  k_pool<<<grid, 256, 0, stream>>>(xg, perm, vals, ATnext ? xp : nullptr, pmax, psum, k,
                                   ATcur, degCur, ATnext, degNext, n);
}

extern "C" void kernel_launch(void* const* d_in, const int* in_sizes, int n_in,
                              void* d_out, int out_size, void* d_ws, size_t ws_size,
                              hipStream_t stream) {
  const float* feature = (const float*)d_in[0];
  const float* img     = (const float*)d_in[1];
  const float* Wp      = (const float*)d_in[2];
  const float* bp      = (const float*)d_in[3];
  const float* ln_f_g  = (const float*)d_in[4];
  const float* ln_f_b  = (const float*)d_in[5];
  const float* ln_p_g  = (const float*)d_in[6];
  const float* ln_p_b  = (const float*)d_in[7];
  const float* W1 = (const float*)d_in[8];   const float* b1 = (const float*)d_in[9];
  const float* Wpool1 = (const float*)d_in[10]; const float* bpool1 = (const float*)d_in[11];
  const float* W2 = (const float*)d_in[12];  const float* b2 = (const float*)d_in[13];
  const float* Wpool2 = (const float*)d_in[14]; const float* bpool2 = (const float*)d_in[15];
  const float* W3 = (const float*)d_in[16];  const float* b3 = (const float*)d_in[17];
  const float* Wpool3 = (const float*)d_in[18]; const float* bpool3 = (const float*)d_in[19];
  float* out = (float*)d_out;
  (void)in_sizes; (void)n_in; (void)out_size; (void)ws_size;

  char* w = (char*)d_ws;
  size_t off = 0;
  auto alloc = [&](size_t bytes) -> char* {
    off = (off + 255) & ~(size_t)255;
    char* p = w + off;
    off += bytes;
    return p;
  };
  float* pos1 = (float*)alloc((size_t)NN * 12 * 4);
  float* x0   = (float*)alloc((size_t)NN * 512 * 4);
  unsigned short* x0h = (unsigned short*)alloc((size_t)NN * 512 * 2);
  float* sqv  = (float*)alloc((size_t)NN * 4);
  unsigned* dmax = (unsigned*)alloc(4);
  float* tileMin = (float*)alloc(528 * 4);
  unsigned* rowMin = (unsigned*)alloc(32 * 4);
  int* degA = (int*)alloc((size_t)NN * 4);
  int* degB = (int*)alloc((size_t)NN * 4);
  float* ybuf = (float*)alloc((size_t)NN * 256 * 4);
  float* xg   = (float*)alloc((size_t)NN * 256 * 4);
  float* xp   = (float*)alloc((size_t)NN * 256 * 4);
  float* y2   = (float*)alloc((size_t)NN * 4);
  float* score= (float*)alloc((size_t)NN * 4);
  int*   perm = (int*)alloc((size_t)NN * 4);
  float* vals = (float*)alloc((size_t)NN * 4);
  float* pmax0 = (float*)alloc(RB * 256 * 4);
  float* psum0 = (float*)alloc(RB * 256 * 4);
  float* pmax1 = (float*)alloc(RB * 256 * 4);
  float* psum1 = (float*)alloc(RB * 256 * 4);
  float* pmax2 = (float*)alloc(RB * 256 * 4);
  float* psum2 = (float*)alloc(RB * 256 * 4);
  unsigned char* ATa = (unsigned char*)alloc((size_t)NN * NN);
  unsigned char* ATb = (unsigned char*)alloc((size_t)3072 * 3072);

  // preamble (pos fused into attn; lnx inits dmax/rowMin/degA)
  k_attn3<<<NN / 8, 256, 0, stream>>>(img, Wp, bp, pos1);
  k_lnx<<<NN, 256, 0, stream>>>(feature, ln_f_g, ln_f_b, pos1, ln_p_g, ln_p_b,
                                x0, x0h, sqv, degA, dmax, rowMin);

  // edge construction via MFMA: max+tileMin+rowMin pass, then alive-gated mask pass
  const int NT = NN / 128, TT = NT * (NT + 1) / 2;  // 32, 528
  k_d2m<false><<<TT, 256, 0, stream>>>(x0h, sqv, dmax, tileMin, rowMin, nullptr, nullptr);
  k_d2m<true><<<TT, 256, 0, stream>>>(x0h, sqv, dmax, tileMin, rowMin, ATa, degA);

  // three GCN + SAGPool + readout layers (readout finalize deferred to k_rfin3)
  run_layer(stream, x0, 4096, 512, W1, b1, Wpool1, bpool1, 3072, ATa, ATb, degA, degB,
            ybuf, xg, xp, y2, score, perm, vals, pmax0, psum0);
  run_layer(stream, xp, 3072, 256, W2, b2, Wpool2, bpool2, 2304, ATb, ATa, degB, degA,
            ybuf, xg, xp, y2, score, perm, vals, pmax1, psum1);
  run_layer(stream, xp, 2304, 256, W3, b3, Wpool3, bpool3, 1728, ATa, nullptr, degA, nullptr,
            ybuf, xg, xp, y2, score, perm, vals, pmax2, psum2);
  k_rfin3<<<1, 256, 0, stream>>>(pmax0, psum0, 3072, pmax1, psum1, 2304,
                                 pmax2, psum2, 1728, out);
}